// Round 6
// baseline (165.686 us; speedup 1.0000x reference)
//
#include <hip/hip_runtime.h>

// Problem constants (hardcoded; spatial_shapes = [[4,8]]*4)
//  bs=64, nq=64, E=256, Hn=8, dh=32, L=4, P=16, BEV=2, Pb=32
//  qb=128 collapses to 64 (queries duplicated). OFF col (h,f,c)=h*256+2f+c;
//  rp level = f&3; image level = f>>5 = wave; attn key = f;
//  output pairs (2q,2q+1) -> rows pj / pj+32.
//
// SINGLE KERNEL: no workspace, no prep. W read strided from L2 (2 MB, hot),
// query/key_hist converted f32->bf16 in-register at point of use.

typedef short  s16x8 __attribute__((ext_vector_type(8)));
typedef float  f32x4 __attribute__((ext_vector_type(4)));

__device__ __forceinline__ unsigned short f2bf(float f) {
    union { float f; unsigned u; } v; v.f = f;
    unsigned r = v.u + 0x7FFFu + ((v.u >> 16) & 1u);   // RNE
    return (unsigned short)(r >> 16);
}
__device__ __forceinline__ float bf2f(unsigned short u) {
    return __uint_as_float(((unsigned)u) << 16);
}
__device__ __forceinline__ s16x8 pack8(const float4 a, const float4 b) {
    s16x8 o;
    o[0] = (short)f2bf(a.x); o[1] = (short)f2bf(a.y);
    o[2] = (short)f2bf(a.z); o[3] = (short)f2bf(a.w);
    o[4] = (short)f2bf(b.x); o[5] = (short)f2bf(b.y);
    o[6] = (short)f2bf(b.z); o[7] = (short)f2bf(b.w);
    return o;
}

// ---------------------------------------------------------------------------
// mega3: one block per (h,b); everything in one launch.
//  logits MFMA (f32->bf16 in-reg frags) -> reg softmax -> attLb bf16 |
//  offsets GEMM (A from query, B from W strided; OFF in registers; no LDS) ->
//  shfl xy-pairing -> bilinear scatter (ds_add_f32) -> bf16 -> AV MFMA ->
//  pair-mean + residual.  LDS 62 KB -> 2 blocks/CU. 4 barriers.
// ---------------------------------------------------------------------------
__global__ __launch_bounds__(256, 2) void mega3(
    const float* __restrict__ query, const float* __restrict__ key_hist,
    const float* __restrict__ value_hist, const float* __restrict__ refp,
    const float* __restrict__ W, const float* __restrict__ bias,
    float* __restrict__ out)
{
    const int h = blockIdx.x, b = blockIdx.y;
    const int t = threadIdx.x, lane = t & 63, wave = t >> 6;
    const int quad = lane >> 4, col = lane & 15;
    const int wq = wave * 16;

    __shared__ __align__(16) short VTl[32 * 136];   // V^T [d][p], 8704 B
    __shared__ __align__(16) short attLb[64 * 136]; // att probs bf16, 17408 B
    __shared__ __align__(16) float rpsL[512];       // refp rows, 2048 B
    __shared__ __align__(16) float AmU[8448];       // 33792 B: Am / Amb alias
    float* Am  = AmU;                               // [64][132] f32
    short* Amb = (short*)AmU;                       // [64][136] bf16

    // ================= Phase 0: zero Am, stage VTl + rps =================
    {
        #pragma unroll
        for (int u = 0; u < 33; ++u) AmU[t + 256 * u] = 0.f;
    }
    {   // VTl[d][p]: values = [query rows | value_hist rows] h-slice, transposed
        const int p = t >> 1, hf = (t & 1) * 16;
        const float* src = ((p < 64) ? query : value_hist) +
                           (size_t)(b * 64 + (p & 63)) * 256 + h * 32 + hf;
        #pragma unroll
        for (int u = 0; u < 4; ++u) {
            const float4 v = *(const float4*)(src + 4 * u);
            VTl[(hf + 4 * u + 0) * 136 + p] = (short)f2bf(v.x);
            VTl[(hf + 4 * u + 1) * 136 + p] = (short)f2bf(v.y);
            VTl[(hf + 4 * u + 2) * 136 + p] = (short)f2bf(v.z);
            VTl[(hf + 4 * u + 3) * 136 + p] = (short)f2bf(v.w);
        }
    }
    rpsL[t]       = refp[(size_t)b * 512 + t];
    rpsL[t + 256] = refp[(size_t)b * 512 + t + 256];

    // ================= Phase 1: logits + softmax -> attLb =================
    {
        const float* qp = query + ((size_t)b * 64 + wq + col) * 256 + h * 32 + quad * 8;
        const s16x8 aq = pack8(*(const float4*)qp, *(const float4*)(qp + 4));
        f32x4 lacc[8];
        #pragma unroll
        for (int t8 = 0; t8 < 8; ++t8) {
            const float* kp = ((t8 < 4)
                ? (query    + ((size_t)b * 64 + 16 * t8 + col) * 256)
                : (key_hist + ((size_t)b * 64 + 16 * (t8 - 4) + col) * 256))
                + h * 32 + quad * 8;
            const s16x8 bk = pack8(*(const float4*)kp, *(const float4*)(kp + 4));
            const f32x4 z = {0.f, 0.f, 0.f, 0.f};
            lacc[t8] = __builtin_amdgcn_mfma_f32_16x16x32_bf16(aq, bk, z, 0, 0, 0);
        }
        #pragma unroll
        for (int r = 0; r < 4; ++r) {
            float m = lacc[0][r];
            #pragma unroll
            for (int t8 = 1; t8 < 8; ++t8) m = fmaxf(m, lacc[t8][r]);
            #pragma unroll
            for (int s = 1; s < 16; s <<= 1) m = fmaxf(m, __shfl_xor(m, s, 64));
            float e[8], ssum = 0.f;
            #pragma unroll
            for (int t8 = 0; t8 < 8; ++t8) {
                e[t8] = __expf(lacc[t8][r] - m); ssum += e[t8];
            }
            #pragma unroll
            for (int s = 1; s < 16; s <<= 1) ssum += __shfl_xor(ssum, s, 64);
            const float inv = 1.0f / ssum;
            const int q = wq + 4 * quad + r;
            #pragma unroll
            for (int t8 = 0; t8 < 8; ++t8)
                attLb[q * 136 + 16 * t8 + col] = (short)f2bf(e[t8] * inv);
        }
    }

    // ================= Phase 2: offsets GEMM, no LDS (OFF in registers) =====
    // wave owns n' in [64*wave, +64): acc[mi][nj]; q = 16mi+4quad+reg,
    // n' = 64*wave + 16nj + col.  A from query f32, B from W f32 strided.
    f32x4 acc[4][4] = {};
    {
        const int nbase = h * 256 + wave * 64;
        #pragma unroll
        for (int kq = 0; kq < 4; ++kq) {
            #pragma unroll
            for (int ks = 0; ks < 2; ++ks) {
                const int k0 = kq * 64 + ks * 32 + quad * 8;
                s16x8 af[4];
                #pragma unroll
                for (int mi = 0; mi < 4; ++mi) {
                    const float* ap = query + ((size_t)b * 64 + 16 * mi + col) * 256 + k0;
                    af[mi] = pack8(*(const float4*)ap, *(const float4*)(ap + 4));
                }
                #pragma unroll
                for (int nj = 0; nj < 4; ++nj) {
                    const float* wp = W + (size_t)k0 * 2048 + nbase + 16 * nj + col;
                    s16x8 bfv;
                    #pragma unroll
                    for (int j = 0; j < 8; ++j)
                        bfv[j] = (short)f2bf(wp[(size_t)j * 2048]);
                    #pragma unroll
                    for (int mi = 0; mi < 4; ++mi)
                        acc[mi][nj] = __builtin_amdgcn_mfma_f32_16x16x32_bf16(
                            af[mi], bfv, acc[mi][nj], 0, 0, 0);
                }
            }
        }
    }
    __syncthreads();   // Am zeroed, attLb/rps/VTl staged

    // ================= Phase 3: scatter =================
    {
        const int i   = col >> 1;          // f-sub 0..7 ; rp level = (f&3)
        const int par = col & 1;           // 0: regs {0,1}, 1: regs {2,3}
        const int base = 32 * wave;        // image level = f>>5 = wave
        #pragma unroll
        for (int nj = 0; nj < 4; ++nj) {
            const float bj = bias[h * 256 + wave * 64 + 16 * nj + col];
            const int f = 32 * wave + 8 * nj + i;
            #pragma unroll
            for (int mi = 0; mi < 4; ++mi) {
                float v[4], p[4];
                #pragma unroll
                for (int r = 0; r < 4; ++r) v[r] = acc[mi][nj][r] + bj;
                #pragma unroll
                for (int r = 0; r < 4; ++r) p[r] = __shfl_xor(v[r], 1, 64);
                #pragma unroll
                for (int rs = 0; rs < 2; ++rs) {
                    const int r = par * 2 + rs;
                    const float ox = par ? p[r] : v[r];
                    const float oy = par ? v[r] : p[r];
                    const int q = 16 * mi + 4 * quad + r;
                    const float2 rp = *(const float2*)&rpsL[q * 8 + (i & 3) * 2];
                    const float a = bf2f((unsigned short)attLb[q * 136 + f]);
                    const float gx = 8.f * (rp.x + ox * 0.125f) - 0.5f;
                    const float gy = 4.f * (rp.y + oy * 0.25f) - 0.5f;
                    const float x0f = floorf(gx), y0f = floorf(gy);
                    const float wx = gx - x0f, wy = gy - y0f;
                    const int x0 = (int)x0f, y0 = (int)y0f;
                    float* rowW = &Am[q * 132 + base];
                    const bool xv0 = (x0 >= 0) && (x0 < 8);
                    const bool xv1 = (x0 >= -1) && (x0 < 7);
                    const bool yv0 = (y0 >= 0) && (y0 < 4);
                    const bool yv1 = (y0 >= -1) && (y0 < 3);
                    if (xv0 && yv0) unsafeAtomicAdd(&rowW[y0 * 8 + x0],           a * (1.f - wx) * (1.f - wy));
                    if (xv1 && yv0) unsafeAtomicAdd(&rowW[y0 * 8 + x0 + 1],       a * wx * (1.f - wy));
                    if (xv0 && yv1) unsafeAtomicAdd(&rowW[(y0 + 1) * 8 + x0],     a * (1.f - wx) * wy);
                    if (xv1 && yv1) unsafeAtomicAdd(&rowW[(y0 + 1) * 8 + x0 + 1], a * wx * wy);
                }
            }
        }
    }
    __syncthreads();

    // ================= Phase 4: Am -> bf16, AV, output =================
    {
        const int cq = t >> 2, cc = (t & 3) * 32;
        float vreg[32];
        #pragma unroll
        for (int u = 0; u < 8; ++u) {
            const float4 v = *(const float4*)&Am[cq * 132 + cc + 4 * u];
            vreg[4 * u + 0] = v.x; vreg[4 * u + 1] = v.y;
            vreg[4 * u + 2] = v.z; vreg[4 * u + 3] = v.w;
        }
        __syncthreads();
        #pragma unroll
        for (int u = 0; u < 4; ++u) {
            s16x8 o;
            #pragma unroll
            for (int j = 0; j < 8; ++j) o[j] = (short)f2bf(vreg[u * 8 + j]);
            *(s16x8*)&Amb[cq * 136 + cc + u * 8] = o;
        }
    }
    __syncthreads();
    {
        f32x4 oacc[2] = {};
        #pragma unroll
        for (int ks = 0; ks < 4; ++ks) {
            const s16x8 af = *(const s16x8*)&Amb[(wq + col) * 136 + ks * 32 + quad * 8];
            #pragma unroll
            for (int n2 = 0; n2 < 2; ++n2) {
                const s16x8 bv = *(const s16x8*)&VTl[(n2 * 16 + col) * 136
                                                     + ks * 32 + quad * 8];
                oacc[n2] = __builtin_amdgcn_mfma_f32_16x16x32_bf16(af, bv, oacc[n2], 0, 0, 0);
            }
        }
        #pragma unroll
        for (int n2 = 0; n2 < 2; ++n2) {
            const int d = h * 32 + n2 * 16 + col;
            #pragma unroll
            for (int pr = 0; pr < 2; ++pr) {
                const float avg = 0.5f * (oacc[n2][2 * pr] + oacc[n2][2 * pr + 1]);
                const int pj = wave * 8 + quad * 2 + pr;
                const size_t re = ((size_t)b * 64 + pj) * 256 + d;
                const size_t ro = ((size_t)b * 64 + pj + 32) * 256 + d;
                out[re] = query[re] + avg;
                out[ro] = query[ro] + avg;
            }
        }
    }
}

extern "C" void kernel_launch(void* const* d_in, const int* in_sizes, int n_in,
                              void* d_out, int out_size, void* d_ws, size_t ws_size,
                              hipStream_t stream) {
    (void)in_sizes; (void)n_in; (void)out_size; (void)d_ws; (void)ws_size;
    const float* query      = (const float*)d_in[0];
    const float* key_hist   = (const float*)d_in[1];
    const float* value_hist = (const float*)d_in[2];
    const float* refp       = (const float*)d_in[3];
    const float* W_off      = (const float*)d_in[5];
    const float* b_off      = (const float*)d_in[6];
    float* out = (float*)d_out;

    mega3<<<dim3(8, 64), 256, 0, stream>>>(query, key_hist, value_hist,
                                           refp, W_off, b_off, out);
}